// Round 5
// baseline (230.379 us; speedup 1.0000x reference)
//
#include <hip/hip_runtime.h>
#include <math.h>

// CRF forward-score scan, faithful to the reference's quirky log_sum_exp
// (max subtracted inside exp indexed by j, max added back indexed by i).
//
// Exact per-step factorization (rowmax bit-exact; rescale/exp refactor
// ~ulp-level), carried in BASE-2 units (x2 == x * log2(e)) so the hardware
// v_exp_f32 / v_log_f32 apply with no log2e/ln2 multiplies on the chain:
//   M2_i   = max_j(fv2_j + tr2_ij)
//   h_j    = exp2(fv2_j - M2_j - feat2_j)      [local to row-group j]
//   fv2'_i = M2_i + 2*feat2_i + log2(sum_j exp(tr_ij) * h_j)
// Terminal converts back: fv = fv2 * ln2.
//
// Structure (audited; 2 barriers + 2 LDS round-trips per step is the floor
// for any multi-wave split since M and dot are both global-over-j reduces):
// B=128 blocks (1 sequence each, independent latency chains), 192 thr = 3 waves.
// Lane map: i = tid>>2 (row 0..47); jsub = tid&3 owns j in [12*jsub,12*jsub+12).
// tr2 / exp(tr) row-slices in VGPRs; fv2_i carried in-register per quad.
// Quad reductions via DPP quad_perm (VALU-only). Barriers are raw s_barrier
// preceded by s_waitcnt lgkmcnt(0) ONLY — no vmcnt(0) drain, so feature
// prefetch loads stay in flight across barriers (m194-m201 pattern).
// Features double-buffered through LDS in 64-step chunks (2 x 12 KB); next
// step's feat is loop-carried (read one step ahead) so p2 = fv2_i - feat2 is
// off the critical path.
//
// Hazard audit: featbuf[buf^1] written at sl==8 (chunk c+1 data); its last
// reader was chunk c-1's featN read at sl==62 (>=14 barriers earlier) -> WAR
// safe. fbn[i] read at sl==63 of the LAST chunk is stale but feeds a dead
// value (loop exits). Initial feat2 read follows the preload barrier.

#define TT 48
#define BB 128
#define SS 512
#define STARTI 46
#define ENDI 47
#define MINV 0.0001f
#define CHUNK 64
#define NCHUNK (SS / CHUNK)   // 8
#define LOG2E 1.44269504088896340736f
#define LN2   0.69314718055994530942f

#if __has_builtin(__builtin_amdgcn_exp2f)
#define EXP2F(x) __builtin_amdgcn_exp2f(x)
#else
#define EXP2F(x) exp2f(x)
#endif
#if __has_builtin(__builtin_amdgcn_logf)   // v_log_f32: log base 2
#define LOG2F(x) __builtin_amdgcn_logf(x)
#else
#define LOG2F(x) log2f(x)
#endif

// quad_perm DPP: cross-lane within each aligned 4-lane group, VALU pipe.
// 0xB1 = [1,0,3,2] (xor 1), 0x4E = [2,3,0,1] (xor 2).
template <int CTRL>
__device__ __forceinline__ float qperm_f(float x) {
#if __has_builtin(__builtin_amdgcn_update_dpp)
    return __int_as_float(__builtin_amdgcn_update_dpp(
        0, __float_as_int(x), CTRL, 0xF, 0xF, true));
#elif __has_builtin(__builtin_amdgcn_mov_dpp)
    return __int_as_float(
        __builtin_amdgcn_mov_dpp(__float_as_int(x), CTRL, 0xF, 0xF, true));
#else
    return __shfl_xor(x, (CTRL == 0xB1) ? 1 : 2, 64);
#endif
}

// Block barrier making LDS ops visible (lgkmcnt(0) covers ds_read AND
// ds_write -> RAW and WAR both safe) without draining global vmcnt.
// LDS accesses are memory ops, so the "memory" clobbers order them around
// the barrier (rule #18's register-only hazard doesn't apply here).
__device__ __forceinline__ void sync_lds() {
    asm volatile("s_waitcnt lgkmcnt(0)" ::: "memory");
    __builtin_amdgcn_s_barrier();
    asm volatile("" ::: "memory");
}

__global__ __launch_bounds__(192, 1) void crf_forward_kernel(
    const float* __restrict__ feats,   // [B, S, T]
    const float* __restrict__ trans,   // [T, T]
    float* __restrict__ out)           // [B]
{
    const int tid  = threadIdx.x;      // 0..191
    const int b    = blockIdx.x;       // 0..127
    const int i    = tid >> 2;         // 0..47
    const int jsub = tid & 3;          // 0..3
    const int j0   = jsub * 12;

    __shared__ __align__(16) float fv2[TT];
    __shared__ __align__(16) float hbuf[TT];
    __shared__ __align__(16) float featbuf[2][CHUNK * TT];   // 2 x 12 KB

    // Per-lane slices: tr2[i][j0..j0+12) = tr*log2e, E = exp(tr). Registers.
    float tr2[12], E[12];
#pragma unroll
    for (int q = 0; q < 3; ++q) {
        float4 v = *reinterpret_cast<const float4*>(trans + i * TT + j0 + 4 * q);
        tr2[4 * q + 0] = v.x * LOG2E; tr2[4 * q + 1] = v.y * LOG2E;
        tr2[4 * q + 2] = v.z * LOG2E; tr2[4 * q + 3] = v.w * LOG2E;
    }
#pragma unroll
    for (int q = 0; q < 12; ++q) E[q] = EXP2F(tr2[q]);   // == exp(tr)

    const float* fb = feats + (size_t)b * SS * TT;

    // fv2_0: MINV*log2e everywhere except 0 at START; also register-carried.
    float fv2i = (i == STARTI) ? 0.0f : (MINV * LOG2E);
    if (tid < TT) fv2[tid] = (tid == STARTI) ? 0.0f : (MINV * LOG2E);

    // Preload chunk 0: 64 steps x 48 = 3072 floats = 192 thr x 4 float4.
#pragma unroll
    for (int k = 0; k < 4; ++k) {
        float4 v = *reinterpret_cast<const float4*>(fb + k * 768 + tid * 4);
        *reinterpret_cast<float4*>(&featbuf[0][k * 768 + tid * 4]) = v;
    }
    sync_lds();

    float feat2 = featbuf[0][i] * LOG2E;   // step-0 feat, loop-carried

    for (int c = 0; c < NCHUNK; ++c) {
        const int buf = c & 1;
        const bool hp = (c + 1 < NCHUNK);
        float4 pf[4];
        if (hp) {
            const float* src = fb + (c + 1) * (CHUNK * TT);
#pragma unroll
            for (int k = 0; k < 4; ++k)
                pf[k] = *reinterpret_cast<const float4*>(src + k * 768 + tid * 4);
        }
        const float* fbb = &featbuf[buf][0];
        const float* fbn = &featbuf[buf ^ 1][0];

#pragma unroll 2
        for (int sl = 0; sl < CHUNK; ++sl) {
            const float p2 = fv2i - feat2;         // ready before the tree
            // Prefetch next step's feat (crosses into next chunk's slot 0 at
            // sl==CHUNK-1; that buffer was written at sl==8 of this chunk).
            const float featN = (sl + 1 < CHUNK) ? fbb[(sl + 1) * TT + i]
                                                 : fbn[i];

            // ---- pass 1: M2 = max over this lane's 12 j of (fv2_j + tr2_ij) ----
            float a[12];
#pragma unroll
            for (int q = 0; q < 3; ++q) {
                float4 v = *reinterpret_cast<const float4*>(&fv2[j0 + 4 * q]);
                a[4 * q + 0] = v.x + tr2[4 * q + 0];
                a[4 * q + 1] = v.y + tr2[4 * q + 1];
                a[4 * q + 2] = v.z + tr2[4 * q + 2];
                a[4 * q + 3] = v.w + tr2[4 * q + 3];
            }
            // depth-3 tree, v_max3-fusable triples
            float m0 = fmaxf(fmaxf(a[0], a[1]),  a[2]);
            float m1 = fmaxf(fmaxf(a[3], a[4]),  a[5]);
            float m2 = fmaxf(fmaxf(a[6], a[7]),  a[8]);
            float m3 = fmaxf(fmaxf(a[9], a[10]), a[11]);
            float M2 = fmaxf(fmaxf(fmaxf(m0, m1), m2), m3);
            M2 = fmaxf(M2, qperm_f<0xB1>(M2));     // quad xor-1
            M2 = fmaxf(M2, qperm_f<0x4E>(M2));     // quad xor-2

            const float h = EXP2F(p2 - M2);        // exp(fv_i - M_i - feat_i)
            if (jsub == 0) hbuf[i] = h;
            const float qv2 = M2 + 2.0f * feat2;   // hides under pass 2
            sync_lds();   // (A) hbuf visible; all fv2 reads of this step done

            // ---- pass 2: dot = sum over this lane's 12 j of E_ij * h_j ----
            float hv[12];
#pragma unroll
            for (int q = 0; q < 3; ++q) {
                float4 v = *reinterpret_cast<const float4*>(&hbuf[j0 + 4 * q]);
                hv[4 * q + 0] = v.x; hv[4 * q + 1] = v.y;
                hv[4 * q + 2] = v.z; hv[4 * q + 3] = v.w;
            }
            float d0 = E[0] * hv[0], d1 = E[1] * hv[1];
            float d2 = E[2] * hv[2], d3 = E[3] * hv[3];
            d0 = fmaf(E[4],  hv[4],  d0); d1 = fmaf(E[5],  hv[5],  d1);
            d2 = fmaf(E[6],  hv[6],  d2); d3 = fmaf(E[7],  hv[7],  d3);
            d0 = fmaf(E[8],  hv[8],  d0); d1 = fmaf(E[9],  hv[9],  d1);
            d2 = fmaf(E[10], hv[10], d2); d3 = fmaf(E[11], hv[11], d3);
            float dot = (d0 + d1) + (d2 + d3);
            dot += qperm_f<0xB1>(dot);
            dot += qperm_f<0x4E>(dot);

            const float nfv = qv2 + LOG2F(dot);
            fv2i = nfv;                            // register carry of fv2_i
            if (jsub == 0) fv2[i] = nfv;

            feat2 = featN * LOG2E;                 // next step's feat, off path

            // Stash next chunk (~8 steps of slack for the global loads; buf^1
            // was fully consumed before this chunk's first barrier).
            if (sl == 8 && hp) {
#pragma unroll
                for (int k = 0; k < 4; ++k)
                    *reinterpret_cast<float4*>(&featbuf[buf ^ 1][k * 768 + tid * 4]) = pf[k];
            }
            sync_lds();   // (B) new fv2 ready; hbuf reads all done
        }
    }

    // ---- terminal: out[b] = LSE_j( fv_j + trans[END][j] ), wave 0 only ----
    if (tid < 64) {
        const float* te = trans + ENDI * TT;
        float sc = (tid < TT) ? fmaf(fv2[tid], LN2, te[tid]) : -3.4e38f;
        float m = sc;
#pragma unroll
        for (int off = 32; off >= 1; off >>= 1)
            m = fmaxf(m, __shfl_xor(m, off));
        float e = (tid < TT) ? __expf(sc - m) : 0.0f;
#pragma unroll
        for (int off = 32; off >= 1; off >>= 1)
            e += __shfl_xor(e, off);
        if (tid == 0) out[b] = m + __logf(e);
    }
}

extern "C" void kernel_launch(void* const* d_in, const int* in_sizes, int n_in,
                              void* d_out, int out_size, void* d_ws, size_t ws_size,
                              hipStream_t stream) {
    (void)in_sizes; (void)n_in; (void)out_size; (void)d_ws; (void)ws_size;
    const float* feats = (const float*)d_in[0];   // [128, 512, 48] f32
    const float* trans = (const float*)d_in[1];   // [48, 48] f32
    float* out = (float*)d_out;                   // [128] f32
    crf_forward_kernel<<<dim3(BB), dim3(192), 0, stream>>>(feats, trans, out);
}